// Round 8
// baseline (232.879 us; speedup 1.0000x reference)
//
#include <hip/hip_runtime.h>
#include <hip/hip_bf16.h>
#include <math.h>

// Multi-Query Attention, B=1, S=2048, D=2048, 16 heads x 128, causal.
// fp32 -> fp16 casts, all matmuls on v_mfma_f32_16x16x32_f16 (fp32 accum).
// R6: GEMMs rebuilt as 128x128 tiles with depth-3 LDS ring + counted
// vmcnt + raw s_barrier (loads span tiles; no vmcnt(0) drain) and
// bijective XCD-aware block swizzle.  (R8 = R6 resubmit; bench timed out twice.)

#define S_LEN 2048
#define DMODEL 2048
#define EQKV 2304
#define HDIM 128
#define NHEADS 16
#define VTS 2080  // padded V^T row stride (f16 elems) -- breaks 4KB channel camping

typedef _Float16 f16;
typedef __attribute__((ext_vector_type(8))) _Float16 f16x8;
typedef __attribute__((ext_vector_type(4))) _Float16 f16x4;
typedef __attribute__((ext_vector_type(4))) float f32x4;

#define MFMA16(a, b, c) __builtin_amdgcn_mfma_f32_16x16x32_f16((a), (b), (c), 0, 0, 0)

// softmax: P = exp2(alpha*s - CFIX); shift-invariant, CFIX constant.
#define ALPHA 0.12751879526655967f  // (1/sqrt(128)) * log2(e)
#define CFIX 10.0f

__device__ __forceinline__ void load_lds16(const void* g, void* l) {
  __builtin_amdgcn_global_load_lds((const __attribute__((address_space(1))) void*)g,
                                   (__attribute__((address_space(3))) void*)l, 16, 0, 0);
}

// ---------------- merged fp32 -> fp16 conversion (3 regions, contiguous dst)
__global__ void cast3_kernel(const float* __restrict__ a, const float* __restrict__ b,
                             const float* __restrict__ c, f16* __restrict__ dst) {
  int i = blockIdx.x * blockDim.x + threadIdx.x;  // 3276800 threads exactly
  const float* src;
  int off;
  if (i < 1048576) { src = a; off = 0; }
  else if (i < 1048576 + 1179648) { src = b; off = 1048576; }
  else { src = c; off = 1048576 + 1179648; }
  float4 v = reinterpret_cast<const float4*>(src)[i - off];
  f16x4 o = {(f16)v.x, (f16)v.y, (f16)v.z, (f16)v.w};
  reinterpret_cast<f16x4*>(dst)[i] = o;
}

// ---------------- GEMM: C[M][N] = A[M][K] * B[N][K]^T + bias --------------
// BM=BN=128, BK=64, 256 thr (2x2 waves, 64x64/wave, 4x4 frags).
// Depth-3 LDS ring (3 x 32KB), counted vmcnt(16) + raw s_barrier per tile:
// stage t+2 issued while computing t; loads stay in flight across 2 tiles.
// XOR-swizzled LDS (chunk ^= row&7), pre-swizzled global source.
// QKV mode: cols 2176..2303 are V -> written transposed (stride VTS) to VT.
__device__ __forceinline__ void gemm_stage(const f16* __restrict__ A,
                                           const f16* __restrict__ Bm,
                                           int arow0, int brow0, int K, int k0,
                                           char* base, int w, int l) {
#pragma unroll
  for (int i = 0; i < 4; ++i) {
    int slot = i * 256 + w * 64 + l;
    int row = slot >> 3;
    int cg = (slot & 7) ^ (row & 7);
    load_lds16(A + (size_t)(arow0 + row) * K + k0 + cg * 8,
               base + (i * 256 + w * 64) * 16);
  }
#pragma unroll
  for (int i = 0; i < 4; ++i) {
    int slot = i * 256 + w * 64 + l;
    int row = slot >> 3;
    int cg = (slot & 7) ^ (row & 7);
    load_lds16(Bm + (size_t)(brow0 + row) * K + k0 + cg * 8,
               base + 16384 + (i * 256 + w * 64) * 16);
  }
}

template <typename OutT, bool QKV>
__global__ __launch_bounds__(256) void gemm_bt(
    const f16* __restrict__ A, const f16* __restrict__ Bm,
    const float* __restrict__ bias, OutT* __restrict__ C,
    f16* __restrict__ VT, int NBN, int N, int K) {
  extern __shared__ char smem[];  // 3 x 32KB ring
  // bijective XCD swizzle (gridDim.x % 8 == 0)
  const int cpx = gridDim.x >> 3;
  const int wg = (blockIdx.x & 7) * cpx + (blockIdx.x >> 3);
  const int bm = wg / NBN, bn = wg % NBN;

  const int tid = threadIdx.x;
  const int w = tid >> 6, l = tid & 63;
  const int wm = w >> 1, wn = w & 1;
  const int lg = l >> 4, lm = l & 15, l7 = l & 7;

  f32x4 acc[4][4] = {};

  int aoff[4][2], boff[4][2];
#pragma unroll
  for (int mf = 0; mf < 4; ++mf) {
    int row = wm * 64 + mf * 16 + lm;
#pragma unroll
    for (int kk = 0; kk < 2; ++kk)
      aoff[mf][kk] = row * 128 + ((kk * 4 + lg) ^ l7) * 16;
  }
#pragma unroll
  for (int nf = 0; nf < 4; ++nf) {
    int row = wn * 64 + nf * 16 + lm;
#pragma unroll
    for (int kk = 0; kk < 2; ++kk)
      boff[nf][kk] = 16384 + row * 128 + ((kk * 4 + lg) ^ l7) * 16;
  }

  const int arow0 = bm * 128, brow0 = bn * 128;
  const int nkt = K >> 6;  // 32

  // prologue: stages 0,1 into ring bufs 0,1 (16 loads/wave in flight)
  gemm_stage(A, Bm, arow0, brow0, K, 0, smem, w, l);
  gemm_stage(A, Bm, arow0, brow0, K, 64, smem + 32768, w, l);

  int rb = 0;  // ring slot of tile t
  for (int t = 0; t < nkt; ++t) {
    __builtin_amdgcn_s_barrier();  // all waves done reading buf being overwritten
    if (t + 2 < nkt) {
      int nb = rb + 2 >= 3 ? rb - 1 : rb + 2;
      gemm_stage(A, Bm, arow0, brow0, K, (t + 2) << 6, smem + nb * 32768, w, l);
      asm volatile("s_waitcnt vmcnt(16)" ::: "memory");  // stage t landed (this wave)
    } else if (t + 1 < nkt) {
      asm volatile("s_waitcnt vmcnt(8)" ::: "memory");
    } else {
      asm volatile("s_waitcnt vmcnt(0)" ::: "memory");
    }
    __builtin_amdgcn_sched_barrier(0);
    __builtin_amdgcn_s_barrier();  // => ALL waves' stage-t writes landed
    char* cur = smem + rb * 32768;
#pragma unroll
    for (int kk = 0; kk < 2; ++kk) {
      f16x8 af[4], bf[4];
#pragma unroll
      for (int mf = 0; mf < 4; ++mf)
        af[mf] = *reinterpret_cast<const f16x8*>(cur + aoff[mf][kk]);
#pragma unroll
      for (int nf = 0; nf < 4; ++nf)
        bf[nf] = *reinterpret_cast<const f16x8*>(cur + boff[nf][kk]);
#pragma unroll
      for (int mf = 0; mf < 4; ++mf)
#pragma unroll
        for (int nf = 0; nf < 4; ++nf)
          acc[mf][nf] = MFMA16(af[mf], bf[nf], acc[mf][nf]);
    }
    rb = rb + 1 >= 3 ? 0 : rb + 1;
  }

#pragma unroll
  for (int mf = 0; mf < 4; ++mf) {
#pragma unroll
    for (int nf = 0; nf < 4; ++nf) {
      int col = bn * 128 + wn * 64 + nf * 16 + lm;
      float bv = bias[col];
#pragma unroll
      for (int j = 0; j < 4; ++j) {
        int row = bm * 128 + wm * 64 + mf * 16 + lg * 4 + j;
        float v = acc[mf][nf][j] + bv;
        if (QKV && col >= DMODEL + HDIM) {
          VT[(size_t)(col - DMODEL - HDIM) * VTS + row] = (f16)v;
        } else {
          C[(size_t)row * N + col] = (OutT)v;
        }
      }
    }
  }
}

// ---------------- shared K/V staging into swizzled LDS --------------------
__device__ __forceinline__ void stage_kv(const f16* __restrict__ qkv,
                                         const f16* __restrict__ vt, int k0,
                                         char* kb, char* vb, int tid, int wv) {
#pragma unroll
  for (int i = 0; i < 4; ++i) {
    int slot = i * 256 + tid;
    int r = slot >> 4;
    int cs = (slot & 15) ^ (r & 7);
    load_lds16(qkv + (size_t)(k0 + r) * EQKV + DMODEL + cs * 8,
               kb + (i * 256 + wv * 64) * 16);
  }
#pragma unroll
  for (int i = 0; i < 4; ++i) {
    int slot = i * 256 + tid;
    int d = slot >> 3;
    int cs = (slot & 7) ^ (d & 7);
    load_lds16(vt + (size_t)d * VTS + k0 + cs * 8,
               vb + (i * 256 + wv * 64) * 16);
  }
}

// ---------------- flash MQA: 4 heads/block, LDS-shared K/V ----------------
__global__ __launch_bounds__(256, 2) void flash_mha4(
    const f16* __restrict__ qkv, const f16* __restrict__ vt, f16* __restrict__ ctx,
    f16* __restrict__ Opart, float* __restrict__ lbuf) {
  const int qt32 = blockIdx.x;
  const int ch = blockIdx.y;
  const int hg = blockIdx.z;
  const int ktiles = (qt32 >> 1) + 1;
  if (ch * 8 >= ktiles) return;

  extern __shared__ char smem[];
  const int tid = threadIdx.x;
  const int wv = tid >> 6;
  const int l = tid & 63;
  const int lg = l >> 4, lm = l & 15;
  char* Pb = smem + 65536 + wv * 4096;
  const int head = hg * 4 + wv;
  const int wq0 = qt32 * 32;

  f16x8 qf[2][4];
#pragma unroll
  for (int mf = 0; mf < 2; ++mf)
#pragma unroll
    for (int ks = 0; ks < 4; ++ks)
      qf[mf][ks] = *reinterpret_cast<const f16x8*>(
          qkv + (size_t)(wq0 + mf * 16 + lm) * EQKV + head * HDIM + ks * 32 + lg * 8);

  f32x4 o[2][8] = {};
  float lsum[2][4] = {};

  const int kt0 = ch * 8;
  const int kt1 = min(ktiles, kt0 + 8);

  stage_kv(qkv, vt, kt0 * 64, smem, smem + 32768, tid, wv);
  int buf = 0;

  for (int t = kt0; t < kt1; ++t) {
    __syncthreads();
    char* kb = smem + buf * 16384;
    char* vb = smem + 32768 + buf * 16384;
    if (t + 1 < kt1)
      stage_kv(qkv, vt, (t + 1) * 64, smem + (buf ^ 1) * 16384,
               smem + 32768 + (buf ^ 1) * 16384, tid, wv);
    const int k0 = t * 64;

    f32x4 sc[2][4] = {};
#pragma unroll
    for (int ks = 0; ks < 4; ++ks) {
#pragma unroll
      for (int nf = 0; nf < 4; ++nf) {
        int row = nf * 16 + lm;
        int pos = (ks * 4 + lg) ^ (row & 7);
        f16x8 kf = *reinterpret_cast<const f16x8*>(kb + row * 256 + pos * 16);
        sc[0][nf] = MFMA16(qf[0][ks], kf, sc[0][nf]);
        sc[1][nf] = MFMA16(qf[1][ks], kf, sc[1][nf]);
      }
    }
    if (t == ktiles - 1) {
#pragma unroll
      for (int mf = 0; mf < 2; ++mf)
#pragma unroll
        for (int nf = 0; nf < 4; ++nf)
#pragma unroll
          for (int j = 0; j < 4; ++j) {
            int row = wq0 + mf * 16 + lg * 4 + j;
            int col = k0 + nf * 16 + lm;
            if (col > row) sc[mf][nf][j] = -__builtin_inff();
          }
    }
#pragma unroll
    for (int mf = 0; mf < 2; ++mf)
#pragma unroll
      for (int nf = 0; nf < 4; ++nf)
#pragma unroll
        for (int j = 0; j < 4; ++j) {
          float p = exp2f(sc[mf][nf][j] * ALPHA - CFIX);
          lsum[mf][j] += p;
          int prow = mf * 16 + lg * 4 + j;
          int c = nf * 2 + (lm >> 3);
          *reinterpret_cast<f16*>(Pb + prow * 128 + ((c ^ (prow & 7)) * 16 + (lm & 7) * 2)) = (f16)p;
        }
    asm volatile("s_waitcnt lgkmcnt(0)" ::: "memory");
    __builtin_amdgcn_sched_barrier(0);
#pragma unroll
    for (int kk = 0; kk < 2; ++kk) {
      f16x8 pa[2];
#pragma unroll
      for (int mf = 0; mf < 2; ++mf) {
        int prow = mf * 16 + lm;
        int pos = (kk * 4 + lg) ^ (prow & 7);
        pa[mf] = *reinterpret_cast<const f16x8*>(Pb + prow * 128 + pos * 16);
      }
#pragma unroll
      for (int df = 0; df < 8; ++df) {
        int d = df * 16 + lm;
        int pos = (kk * 4 + lg) ^ (d & 7);
        f16x8 vf = *reinterpret_cast<const f16x8*>(vb + d * 128 + pos * 16);
        o[0][df] = MFMA16(pa[0], vf, o[0][df]);
        o[1][df] = MFMA16(pa[1], vf, o[1][df]);
      }
    }
    buf ^= 1;
  }

#pragma unroll
  for (int mf = 0; mf < 2; ++mf)
#pragma unroll
    for (int j = 0; j < 4; ++j) {
#pragma unroll
      for (int d = 1; d < 16; d <<= 1) lsum[mf][j] += __shfl_xor(lsum[mf][j], d);
    }

  if (qt32 < 16) {
#pragma unroll
    for (int mf = 0; mf < 2; ++mf)
#pragma unroll
      for (int j = 0; j < 4; ++j) {
        float inv = 1.0f / lsum[mf][j];
        int row = wq0 + mf * 16 + lg * 4 + j;
#pragma unroll
        for (int df = 0; df < 8; ++df)
          ctx[(size_t)row * DMODEL + head * HDIM + df * 16 + lm] =
              (f16)(o[mf][df][j] * inv);
      }
  } else {
    const int slot = head * 192 + (qt32 - 16) * 4 + ch;
    f16* Op = Opart + (size_t)slot * 4096;
    float* lp = lbuf + (size_t)slot * 32;
#pragma unroll
    for (int mf = 0; mf < 2; ++mf)
#pragma unroll
      for (int j = 0; j < 4; ++j) {
        int rl = mf * 16 + lg * 4 + j;
#pragma unroll
        for (int df = 0; df < 8; ++df)
          Op[rl * 128 + df * 16 + lm] = (f16)o[mf][df][j];
        if (lm == 0) lp[rl] = lsum[mf][j];
      }
  }
}

// ---------------- combine partial chunks (plain sums) ---------------------
__global__ __launch_bounds__(128) void flash_combine(
    const f16* __restrict__ Opart, const float* __restrict__ lbuf,
    f16* __restrict__ ctx) {
  const int qt32 = blockIdx.x, head = blockIdx.y;
  if (qt32 < 16) return;
  const int ktiles = (qt32 >> 1) + 1;
  const int nch = (ktiles + 7) >> 3;
  const int tid = threadIdx.x;
  const int row = tid >> 2, cg = tid & 3;
  const int slot0 = head * 192 + (qt32 - 16) * 4;

  float L = 0.f;
  for (int i = 0; i < nch; ++i) L += lbuf[(size_t)(slot0 + i) * 32 + row];
  const float invL = 1.0f / L;
  const int rowg = qt32 * 32 + row;

#pragma unroll
  for (int g = 0; g < 4; ++g) {
    float acc[8] = {0.f, 0.f, 0.f, 0.f, 0.f, 0.f, 0.f, 0.f};
    for (int i = 0; i < nch; ++i) {
      f16x8 v = *reinterpret_cast<const f16x8*>(
          Opart + (size_t)(slot0 + i) * 4096 + row * 128 + cg * 32 + g * 8);
#pragma unroll
      for (int j = 0; j < 8; ++j) acc[j] += (float)v[j];
    }
    f16x8 ov;
#pragma unroll
    for (int j = 0; j < 8; ++j) ov[j] = (f16)(acc[j] * invL);
    *reinterpret_cast<f16x8*>(ctx + (size_t)rowg * DMODEL + head * HDIM + cg * 32 + g * 8) = ov;
  }
}

// ---------------- host launcher -------------------------------------------
extern "C" void kernel_launch(void* const* d_in, const int* in_sizes, int n_in,
                              void* d_out, int out_size, void* d_ws, size_t ws_size,
                              hipStream_t stream) {
  const float* x = (const float*)d_in[0];
  const float* Wqkv_w = (const float*)d_in[1];
  const float* Wqkv_b = (const float*)d_in[2];
  const float* out_w = (const float*)d_in[3];
  const float* out_b = (const float*)d_in[4];

  char* p = (char*)d_ws;
  f16* xh = (f16*)p;    p += (size_t)S_LEN * DMODEL * 2;
  f16* wqh = (f16*)p;   p += (size_t)EQKV * DMODEL * 2;
  f16* owh = (f16*)p;   p += (size_t)DMODEL * DMODEL * 2;
  f16* qkvh = (f16*)p;  p += (size_t)S_LEN * EQKV * 2;
  f16* vth = (f16*)p;   p += (size_t)HDIM * VTS * 2;
  f16* ctxh = (f16*)p;  p += (size_t)S_LEN * DMODEL * 2;
  f16* Opart = (f16*)p;   p += (size_t)3072 * 4096 * 2;
  float* lbuf = (float*)p; p += (size_t)3072 * 32 * 4;

  cast3_kernel<<<12800, 256, 0, stream>>>(x, Wqkv_w, out_w, xh);

  // QKV: M=2048 (16 bm) x N=2304 (18 bn) -> 288 blocks (288 % 8 == 0)
  gemm_bt<f16, true><<<288, 256, 98304, stream>>>(
      xh, wqh, Wqkv_b, qkvh, vth, 18, EQKV, DMODEL);

  flash_mha4<<<dim3(64, 4, 4), 256, 81920, stream>>>(qkvh, vth, ctxh, Opart, lbuf);
  flash_combine<<<dim3(64, 16), 128, 0, stream>>>(Opart, lbuf, ctxh);

  // out: M=2048 x N=2048 -> 16x16 = 256 blocks (256 % 8 == 0)
  gemm_bt<float, false><<<256, 256, 98304, stream>>>(
      ctxh, owh, out_b, (float*)d_out, nullptr, 16, DMODEL, DMODEL);
}

// Round 9
// 207.193 us; speedup vs baseline: 1.1240x; 1.1240x over previous
//
#include <hip/hip_runtime.h>
#include <hip/hip_bf16.h>
#include <math.h>

// Multi-Query Attention, B=1, S=2048, D=2048, 16 heads x 128, causal.
// fp32 -> fp16 casts, all matmuls on v_mfma_f32_16x16x32_f16 (fp32 accum).
// R9: GEMMs reverted to the proven R5 structure (64x128 tile, 48KB dbuf,
// 3 blocks/CU, stage-before-compute + single barrier = T3 minimum 2-phase)
// + bijective XCD swizzle kept from R6. Flash gains s_setprio around MFMA
// clusters (T5, measured +4-7% on attention-shaped kernels).

#define S_LEN 2048
#define DMODEL 2048
#define EQKV 2304
#define HDIM 128
#define NHEADS 16
#define VTS 2080  // padded V^T row stride (f16 elems) -- breaks 4KB channel camping

typedef _Float16 f16;
typedef __attribute__((ext_vector_type(8))) _Float16 f16x8;
typedef __attribute__((ext_vector_type(4))) _Float16 f16x4;
typedef __attribute__((ext_vector_type(4))) float f32x4;

#define MFMA16(a, b, c) __builtin_amdgcn_mfma_f32_16x16x32_f16((a), (b), (c), 0, 0, 0)

// softmax: P = exp2(alpha*s - CFIX); shift-invariant, CFIX constant.
#define ALPHA 0.12751879526655967f  // (1/sqrt(128)) * log2(e)
#define CFIX 10.0f

__device__ __forceinline__ void load_lds16(const void* g, void* l) {
  __builtin_amdgcn_global_load_lds((const __attribute__((address_space(1))) void*)g,
                                   (__attribute__((address_space(3))) void*)l, 16, 0, 0);
}

// ---------------- merged fp32 -> fp16 conversion (3 regions, contiguous dst)
__global__ void cast3_kernel(const float* __restrict__ a, const float* __restrict__ b,
                             const float* __restrict__ c, f16* __restrict__ dst) {
  int i = blockIdx.x * blockDim.x + threadIdx.x;  // 3276800 threads exactly
  const float* src;
  int off;
  if (i < 1048576) { src = a; off = 0; }
  else if (i < 1048576 + 1179648) { src = b; off = 1048576; }
  else { src = c; off = 1048576 + 1179648; }
  float4 v = reinterpret_cast<const float4*>(src)[i - off];
  f16x4 o = {(f16)v.x, (f16)v.y, (f16)v.z, (f16)v.w};
  reinterpret_cast<f16x4*>(dst)[i] = o;
}

// ---------------- GEMM: C[M][N] = A[M][K] * B[N][K]^T + bias --------------
// BM=64 BN=128 BK=64, 256 thr (2x2 waves of 32x64), 48KB LDS double buffer,
// stage-next-then-compute + ONE __syncthreads per tile (T3 minimum 2-phase:
// the end-of-tile vmcnt(0) drains loads that overlapped the whole compute).
// XOR-swizzled LDS (chunk ^= row&7), pre-swizzled global source.
// Bijective XCD swizzle on a 1D grid (gridDim.x % 8 == 0).
// QKV mode: cols 2176..2303 are V -> written transposed (stride VTS) to VT.
__device__ __forceinline__ void gemm_stage(const f16* __restrict__ A,
                                           const f16* __restrict__ Bm,
                                           int bm, int bn, int K, int k0,
                                           char* base, int w, int l) {
#pragma unroll
  for (int i = 0; i < 2; ++i) {
    int slot = i * 256 + w * 64 + l;
    int row = slot >> 3;
    int cg = (slot & 7) ^ (row & 7);
    load_lds16(A + (size_t)(bm * 64 + row) * K + k0 + cg * 8,
               base + (i * 256 + w * 64) * 16);
  }
#pragma unroll
  for (int i = 0; i < 4; ++i) {
    int slot = i * 256 + w * 64 + l;
    int row = slot >> 3;
    int cg = (slot & 7) ^ (row & 7);
    load_lds16(Bm + (size_t)(bn * 128 + row) * K + k0 + cg * 8,
               base + 8192 + (i * 256 + w * 64) * 16);
  }
}

template <typename OutT, bool QKV>
__global__ __launch_bounds__(256) void gemm_bt(
    const f16* __restrict__ A, const f16* __restrict__ Bm,
    const float* __restrict__ bias, OutT* __restrict__ C,
    f16* __restrict__ VT, int NBN, int N, int K) {
  __shared__ __align__(16) char smem[49152];  // 2 x (A 8KB + B 16KB)
  // bijective XCD swizzle (gridDim.x % 8 == 0)
  const int cpx = gridDim.x >> 3;
  const int wg = (blockIdx.x & 7) * cpx + (blockIdx.x >> 3);
  const int bm = wg / NBN, bn = wg % NBN;

  const int tid = threadIdx.x;
  const int w = tid >> 6;
  const int l = tid & 63;
  const int wm = w >> 1, wn = w & 1;
  const int lg = l >> 4;
  const int lm = l & 15;
  const int l7 = l & 7;

  f32x4 acc[2][4] = {};

  int aoff[2][2], boff[4][2];
#pragma unroll
  for (int mf = 0; mf < 2; ++mf) {
    int row = wm * 32 + mf * 16 + lm;
#pragma unroll
    for (int kk = 0; kk < 2; ++kk)
      aoff[mf][kk] = row * 128 + ((kk * 4 + lg) ^ l7) * 16;
  }
#pragma unroll
  for (int nf = 0; nf < 4; ++nf) {
    int row = wn * 64 + nf * 16 + lm;
#pragma unroll
    for (int kk = 0; kk < 2; ++kk)
      boff[nf][kk] = 8192 + row * 128 + ((kk * 4 + lg) ^ l7) * 16;
  }

  const int nkt = K >> 6;
  // prologue: stage tile 0 into buffer 0, drain, barrier
  gemm_stage(A, Bm, bm, bn, K, 0, smem, w, l);
  __syncthreads();
  int buf = 0;
  for (int kt = 0; kt < nkt; ++kt) {
    char* cur = smem + buf * 24576;
    if (kt + 1 < nkt)  // issue next-tile loads first (overlap with compute)
      gemm_stage(A, Bm, bm, bn, K, (kt + 1) << 6, smem + (buf ^ 1) * 24576, w, l);
#pragma unroll
    for (int kk = 0; kk < 2; ++kk) {
      f16x8 af[2], bf[4];
#pragma unroll
      for (int mf = 0; mf < 2; ++mf)
        af[mf] = *reinterpret_cast<const f16x8*>(cur + aoff[mf][kk]);
#pragma unroll
      for (int nf = 0; nf < 4; ++nf)
        bf[nf] = *reinterpret_cast<const f16x8*>(cur + boff[nf][kk]);
#pragma unroll
      for (int mf = 0; mf < 2; ++mf)
#pragma unroll
        for (int nf = 0; nf < 4; ++nf)
          acc[mf][nf] = MFMA16(af[mf], bf[nf], acc[mf][nf]);
    }
    __syncthreads();  // vmcnt(0): next-tile loads landed (overlapped); reads done
    buf ^= 1;
  }

#pragma unroll
  for (int mf = 0; mf < 2; ++mf) {
#pragma unroll
    for (int nf = 0; nf < 4; ++nf) {
      int col = bn * 128 + wn * 64 + nf * 16 + lm;
      float bv = bias[col];
#pragma unroll
      for (int j = 0; j < 4; ++j) {
        int row = bm * 64 + wm * 32 + mf * 16 + lg * 4 + j;
        float v = acc[mf][nf][j] + bv;
        if (QKV && col >= DMODEL + HDIM) {
          VT[(size_t)(col - DMODEL - HDIM) * VTS + row] = (f16)v;
        } else {
          C[(size_t)row * N + col] = (OutT)v;
        }
      }
    }
  }
}

// ---------------- shared K/V staging into swizzled LDS --------------------
__device__ __forceinline__ void stage_kv(const f16* __restrict__ qkv,
                                         const f16* __restrict__ vt, int k0,
                                         char* kb, char* vb, int tid, int wv) {
#pragma unroll
  for (int i = 0; i < 4; ++i) {
    int slot = i * 256 + tid;
    int r = slot >> 4;
    int cs = (slot & 15) ^ (r & 7);
    load_lds16(qkv + (size_t)(k0 + r) * EQKV + DMODEL + cs * 8,
               kb + (i * 256 + wv * 64) * 16);
  }
#pragma unroll
  for (int i = 0; i < 4; ++i) {
    int slot = i * 256 + tid;
    int d = slot >> 3;
    int cs = (slot & 7) ^ (d & 7);
    load_lds16(vt + (size_t)d * VTS + k0 + cs * 8,
               vb + (i * 256 + wv * 64) * 16);
  }
}

// ---------------- flash MQA: 4 heads/block, LDS-shared K/V ----------------
// grid (qt32=64, ch=4, hg=4), block 256 thr = 4 waves, wave = head hg*4+wv.
// Dynamic LDS 80KB: K dbuf 2x16K | V dbuf 2x16K | P 4x4K (per wave).
// s_setprio(1) around MFMA clusters (T5: blocks at different phases).
__global__ __launch_bounds__(256, 2) void flash_mha4(
    const f16* __restrict__ qkv, const f16* __restrict__ vt, f16* __restrict__ ctx,
    f16* __restrict__ Opart, float* __restrict__ lbuf) {
  const int qt32 = blockIdx.x;
  const int ch = blockIdx.y;
  const int hg = blockIdx.z;
  const int ktiles = (qt32 >> 1) + 1;
  if (ch * 8 >= ktiles) return;

  extern __shared__ char smem[];
  const int tid = threadIdx.x;
  const int wv = tid >> 6;
  const int l = tid & 63;
  const int lg = l >> 4, lm = l & 15;
  char* Pb = smem + 65536 + wv * 4096;
  const int head = hg * 4 + wv;
  const int wq0 = qt32 * 32;

  f16x8 qf[2][4];
#pragma unroll
  for (int mf = 0; mf < 2; ++mf)
#pragma unroll
    for (int ks = 0; ks < 4; ++ks)
      qf[mf][ks] = *reinterpret_cast<const f16x8*>(
          qkv + (size_t)(wq0 + mf * 16 + lm) * EQKV + head * HDIM + ks * 32 + lg * 8);

  f32x4 o[2][8] = {};
  float lsum[2][4] = {};

  const int kt0 = ch * 8;
  const int kt1 = min(ktiles, kt0 + 8);

  stage_kv(qkv, vt, kt0 * 64, smem, smem + 32768, tid, wv);
  int buf = 0;

  for (int t = kt0; t < kt1; ++t) {
    __syncthreads();
    char* kb = smem + buf * 16384;
    char* vb = smem + 32768 + buf * 16384;
    if (t + 1 < kt1)
      stage_kv(qkv, vt, (t + 1) * 64, smem + (buf ^ 1) * 16384,
               smem + 32768 + (buf ^ 1) * 16384, tid, wv);
    const int k0 = t * 64;

    f32x4 sc[2][4] = {};
    __builtin_amdgcn_s_setprio(1);
#pragma unroll
    for (int ks = 0; ks < 4; ++ks) {
#pragma unroll
      for (int nf = 0; nf < 4; ++nf) {
        int row = nf * 16 + lm;
        int pos = (ks * 4 + lg) ^ (row & 7);
        f16x8 kf = *reinterpret_cast<const f16x8*>(kb + row * 256 + pos * 16);
        sc[0][nf] = MFMA16(qf[0][ks], kf, sc[0][nf]);
        sc[1][nf] = MFMA16(qf[1][ks], kf, sc[1][nf]);
      }
    }
    __builtin_amdgcn_s_setprio(0);
    if (t == ktiles - 1) {
#pragma unroll
      for (int mf = 0; mf < 2; ++mf)
#pragma unroll
        for (int nf = 0; nf < 4; ++nf)
#pragma unroll
          for (int j = 0; j < 4; ++j) {
            int row = wq0 + mf * 16 + lg * 4 + j;
            int col = k0 + nf * 16 + lm;
            if (col > row) sc[mf][nf][j] = -__builtin_inff();
          }
    }
#pragma unroll
    for (int mf = 0; mf < 2; ++mf)
#pragma unroll
      for (int nf = 0; nf < 4; ++nf)
#pragma unroll
        for (int j = 0; j < 4; ++j) {
          float p = exp2f(sc[mf][nf][j] * ALPHA - CFIX);
          lsum[mf][j] += p;
          int prow = mf * 16 + lg * 4 + j;
          int c = nf * 2 + (lm >> 3);
          *reinterpret_cast<f16*>(Pb + prow * 128 + ((c ^ (prow & 7)) * 16 + (lm & 7) * 2)) = (f16)p;
        }
    asm volatile("s_waitcnt lgkmcnt(0)" ::: "memory");
    __builtin_amdgcn_sched_barrier(0);
    __builtin_amdgcn_s_setprio(1);
#pragma unroll
    for (int kk = 0; kk < 2; ++kk) {
      f16x8 pa[2];
#pragma unroll
      for (int mf = 0; mf < 2; ++mf) {
        int prow = mf * 16 + lm;
        int pos = (kk * 4 + lg) ^ (prow & 7);
        pa[mf] = *reinterpret_cast<const f16x8*>(Pb + prow * 128 + pos * 16);
      }
#pragma unroll
      for (int df = 0; df < 8; ++df) {
        int d = df * 16 + lm;
        int pos = (kk * 4 + lg) ^ (d & 7);
        f16x8 vf = *reinterpret_cast<const f16x8*>(vb + d * 128 + pos * 16);
        o[0][df] = MFMA16(pa[0], vf, o[0][df]);
        o[1][df] = MFMA16(pa[1], vf, o[1][df]);
      }
    }
    __builtin_amdgcn_s_setprio(0);
    buf ^= 1;
  }

#pragma unroll
  for (int mf = 0; mf < 2; ++mf)
#pragma unroll
    for (int j = 0; j < 4; ++j) {
#pragma unroll
      for (int d = 1; d < 16; d <<= 1) lsum[mf][j] += __shfl_xor(lsum[mf][j], d);
    }

  if (qt32 < 16) {
#pragma unroll
    for (int mf = 0; mf < 2; ++mf)
#pragma unroll
      for (int j = 0; j < 4; ++j) {
        float inv = 1.0f / lsum[mf][j];
        int row = wq0 + mf * 16 + lg * 4 + j;
#pragma unroll
        for (int df = 0; df < 8; ++df)
          ctx[(size_t)row * DMODEL + head * HDIM + df * 16 + lm] =
              (f16)(o[mf][df][j] * inv);
      }
  } else {
    const int slot = head * 192 + (qt32 - 16) * 4 + ch;
    f16* Op = Opart + (size_t)slot * 4096;
    float* lp = lbuf + (size_t)slot * 32;
#pragma unroll
    for (int mf = 0; mf < 2; ++mf)
#pragma unroll
      for (int j = 0; j < 4; ++j) {
        int rl = mf * 16 + lg * 4 + j;
#pragma unroll
        for (int df = 0; df < 8; ++df)
          Op[rl * 128 + df * 16 + lm] = (f16)o[mf][df][j];
        if (lm == 0) lp[rl] = lsum[mf][j];
      }
  }
}

// ---------------- combine partial chunks (plain sums) ---------------------
__global__ __launch_bounds__(128) void flash_combine(
    const f16* __restrict__ Opart, const float* __restrict__ lbuf,
    f16* __restrict__ ctx) {
  const int qt32 = blockIdx.x, head = blockIdx.y;
  if (qt32 < 16) return;
  const int ktiles = (qt32 >> 1) + 1;
  const int nch = (ktiles + 7) >> 3;
  const int tid = threadIdx.x;
  const int row = tid >> 2, cg = tid & 3;
  const int slot0 = head * 192 + (qt32 - 16) * 4;

  float L = 0.f;
  for (int i = 0; i < nch; ++i) L += lbuf[(size_t)(slot0 + i) * 32 + row];
  const float invL = 1.0f / L;
  const int rowg = qt32 * 32 + row;

#pragma unroll
  for (int g = 0; g < 4; ++g) {
    float acc[8] = {0.f, 0.f, 0.f, 0.f, 0.f, 0.f, 0.f, 0.f};
    for (int i = 0; i < nch; ++i) {
      f16x8 v = *reinterpret_cast<const f16x8*>(
          Opart + (size_t)(slot0 + i) * 4096 + row * 128 + cg * 32 + g * 8);
#pragma unroll
      for (int j = 0; j < 8; ++j) acc[j] += (float)v[j];
    }
    f16x8 ov;
#pragma unroll
    for (int j = 0; j < 8; ++j) ov[j] = (f16)(acc[j] * invL);
    *reinterpret_cast<f16x8*>(ctx + (size_t)rowg * DMODEL + head * HDIM + cg * 32 + g * 8) = ov;
  }
}

// ---------------- host launcher -------------------------------------------
extern "C" void kernel_launch(void* const* d_in, const int* in_sizes, int n_in,
                              void* d_out, int out_size, void* d_ws, size_t ws_size,
                              hipStream_t stream) {
  const float* x = (const float*)d_in[0];
  const float* Wqkv_w = (const float*)d_in[1];
  const float* Wqkv_b = (const float*)d_in[2];
  const float* out_w = (const float*)d_in[3];
  const float* out_b = (const float*)d_in[4];

  char* p = (char*)d_ws;
  f16* xh = (f16*)p;    p += (size_t)S_LEN * DMODEL * 2;
  f16* wqh = (f16*)p;   p += (size_t)EQKV * DMODEL * 2;
  f16* owh = (f16*)p;   p += (size_t)DMODEL * DMODEL * 2;
  f16* qkvh = (f16*)p;  p += (size_t)S_LEN * EQKV * 2;
  f16* vth = (f16*)p;   p += (size_t)HDIM * VTS * 2;
  f16* ctxh = (f16*)p;  p += (size_t)S_LEN * DMODEL * 2;
  f16* Opart = (f16*)p;   p += (size_t)3072 * 4096 * 2;
  float* lbuf = (float*)p; p += (size_t)3072 * 32 * 4;

  cast3_kernel<<<12800, 256, 0, stream>>>(x, Wqkv_w, out_w, xh);

  // QKV: M=2048 (32 bm of 64) x N=2304 (18 bn of 128) -> 576 blocks (%8==0)
  gemm_bt<f16, true><<<576, 256, 0, stream>>>(
      xh, wqh, Wqkv_b, qkvh, vth, 18, EQKV, DMODEL);

  flash_mha4<<<dim3(64, 4, 4), 256, 81920, stream>>>(qkvh, vth, ctxh, Opart, lbuf);
  flash_combine<<<dim3(64, 16), 128, 0, stream>>>(Opart, lbuf, ctxh);

  // out: M=2048 (32 bm) x N=2048 (16 bn) -> 512 blocks (%8==0)
  gemm_bt<float, false><<<512, 256, 0, stream>>>(
      ctxh, owh, out_b, (float*)d_out, nullptr, 16, DMODEL, DMODEL);
}